// Round 7
// baseline (1057.552 us; speedup 1.0000x reference)
//
#include <hip/hip_runtime.h>
#include <math.h>

#define BB 512
#define NN 128
#define DD 256
#define HH 8
#define NC 5
#define BH 64
#define SCALE_INV 0.17677669529663687f  // 1/sqrt(32)

// One-shot transpose of pWq and eWq (256x256 each) so prep2's U5 loop reads
// them coalesced.
__global__ __launch_bounds__(256) void transpose_kernel(
  const float* __restrict__ A, const float* __restrict__ B,
  float* __restrict__ AT, float* __restrict__ BT)
{
  __shared__ float tile[32][33];
  int bx = blockIdx.x, by = blockIdx.y, z = blockIdx.z;
  const float* src = z ? B : A;
  float* dst = z ? BT : AT;
  int tx = threadIdx.x & 31, ty = threadIdx.x >> 5;
  #pragma unroll
  for (int k=0;k<4;++k)
    tile[ty+8*k][tx] = src[(size_t)(by*32+ty+8*k)*DD + bx*32+tx];
  __syncthreads();
  #pragma unroll
  for (int k=0;k<4;++k)
    dst[(size_t)(bx*32+ty+8*k)*DD + by*32+tx] = tile[tx][ty+8*k];
}

// prep1: 512 threads, NO barriers. Wave 0: LN1->Ve->v2 (wave-local chain).
// Waves 1-7: redundant wave-local top-5, then disjoint bias-table slices.
__global__ __launch_bounds__(512) void prep1_kernel(
  const float* __restrict__ tokens, const int* __restrict__ ego_idx,
  const float* __restrict__ dist,
  const float* __restrict__ ln1_g, const float* __restrict__ ln1_b,
  const float* __restrict__ cWv, const float* __restrict__ cWo,
  const float* __restrict__ bW1, const float* __restrict__ bb1,
  const float* __restrict__ bW2, const float* __restrict__ bb2,
  float* __restrict__ v2g, int* __restrict__ candI,
  float* __restrict__ biasO)
{
  int b = blockIdx.x, t = threadIdx.x;
  int lane = t & 63, wave = t >> 6;
  int ego = ego_idx[b];

  if (wave == 0){
    // ---- LN1(ego): x1 distributed 4 elems/lane ----
    float4 xe = *(const float4*)(tokens + ((size_t)b*NN+ego)*DD + 4*lane);
    float s1 = xe.x+xe.y+xe.z+xe.w;
    float s2 = xe.x*xe.x+xe.y*xe.y+xe.z*xe.z+xe.w*xe.w;
    #pragma unroll
    for (int m=32;m>=1;m>>=1){ s1+=__shfl_xor(s1,m); s2+=__shfl_xor(s2,m); }
    float mu = s1*(1.0f/DD), var = s2*(1.0f/DD)-mu*mu;
    float rs = rsqrtf(var+1e-5f);
    float4 g = *(const float4*)(ln1_g + 4*lane);
    float4 bb = *(const float4*)(ln1_b + 4*lane);
    float x10=(xe.x-mu)*rs*g.x+bb.x;
    float x11=(xe.y-mu)*rs*g.y+bb.y;
    float x12=(xe.z-mu)*rs*g.z+bb.z;
    float x13=(xe.w-mu)*rs*g.w+bb.w;
    // ---- Ve[t]=sum_d x1[d]*cWv[d][t], t=4*lane+j ----
    float a0=0,a1=0,a2=0,a3=0;
    #pragma unroll 2
    for (int d0=0; d0<DD; d0+=4){
      int src = d0>>2;
      float c0=__shfl(x10,src), c1=__shfl(x11,src), c2=__shfl(x12,src), c3=__shfl(x13,src);
      float4 w0=*(const float4*)(cWv + (size_t)(d0  )*DD + 4*lane);
      float4 w1=*(const float4*)(cWv + (size_t)(d0+1)*DD + 4*lane);
      float4 w2=*(const float4*)(cWv + (size_t)(d0+2)*DD + 4*lane);
      float4 w3=*(const float4*)(cWv + (size_t)(d0+3)*DD + 4*lane);
      a0 += c0*w0.x + c1*w1.x + c2*w2.x + c3*w3.x;
      a1 += c0*w0.y + c1*w1.y + c2*w2.y + c3*w3.y;
      a2 += c0*w0.z + c1*w1.z + c2*w2.z + c3*w3.z;
      a3 += c0*w0.w + c1*w1.w + c2*w2.w + c3*w3.w;
    }
    // ---- v2 = Ve @ cWo ----
    float e0=0,e1=0,e2=0,e3=0;
    #pragma unroll 2
    for (int d0=0; d0<DD; d0+=4){
      int src = d0>>2;
      float c0=__shfl(a0,src), c1=__shfl(a1,src), c2=__shfl(a2,src), c3=__shfl(a3,src);
      float4 w0=*(const float4*)(cWo + (size_t)(d0  )*DD + 4*lane);
      float4 w1=*(const float4*)(cWo + (size_t)(d0+1)*DD + 4*lane);
      float4 w2=*(const float4*)(cWo + (size_t)(d0+2)*DD + 4*lane);
      float4 w3=*(const float4*)(cWo + (size_t)(d0+3)*DD + 4*lane);
      e0 += c0*w0.x + c1*w1.x + c2*w2.x + c3*w3.x;
      e1 += c0*w0.y + c1*w1.y + c2*w2.y + c3*w3.y;
      e2 += c0*w0.z + c1*w1.z + c2*w2.z + c3*w3.z;
      e3 += c0*w0.w + c1*w1.w + c2*w2.w + c3*w3.w;
    }
    *(float4*)(v2g + (size_t)b*DD + 4*lane) = make_float4(e0,e1,e2,e3);
  } else {
    // ---- wave-local top-5 (redundant per wave) ----
    unsigned long long kk0 = (((unsigned long long)__float_as_uint(dist[b*NN+lane]))<<32) | (unsigned)lane;
    unsigned long long kk1 = (((unsigned long long)__float_as_uint(dist[b*NN+lane+64]))<<32) | (unsigned)(lane+64);
    int ci0,ci1,ci2,ci3,ci4; float cd0,cd1,cd2,cd3,cd4;
    #define TOP5ROUND(CI,CD) { \
      unsigned long long m_ = kk0<kk1?kk0:kk1; \
      _Pragma("unroll") \
      for (int s_=32;s_>=1;s_>>=1){ unsigned long long o_=__shfl_xor(m_,s_); if(o_<m_)m_=o_; } \
      CI = (int)(m_ & 0xffffffffULL); CD = __uint_as_float((unsigned)(m_>>32)); \
      if (CI==lane) kk0=~0ULL; if (CI==lane+64) kk1=~0ULL; }
    TOP5ROUND(ci0,cd0)
    TOP5ROUND(ci1,cd1)
    TOP5ROUND(ci2,cd2)
    TOP5ROUND(ci3,cd3)
    TOP5ROUND(ci4,cd4)
    #undef TOP5ROUND
    if (wave==1 && lane==0){
      candI[b*8+0]=ci0; candI[b*8+1]=ci1; candI[b*8+2]=ci2;
      candI[b*8+3]=ci3; candI[b*8+4]=ci4;
    }
    // ---- bias table slices: 640 outputs over waves 1-7, two rounds ----
    float4 z0 = *(const float4*)(bb2);
    float4 z1 = *(const float4*)(bb2+4);
    #pragma unroll 1
    for (int rnd=0; rnd<2; ++rnd){
      int p = (rnd==0) ? (wave-1)*64 + lane : 448 + (wave-1)*64 + lane;
      if (p >= NN*NC) continue;     // wave-uniform skip in round 1
      unsigned n = (unsigned)p / NC;
      int c = p - (int)n*NC;
      float dj = (c==0)?cd0:(c==1)?cd1:(c==2)?cd2:(c==3)?cd3:cd4;
      float di = dist[b*NN + n];
      float o0=0,o1=0,o2=0,o3=0,o4=0,o5=0,o6=0,o7=0;
      #pragma unroll 4
      for (int j=0;j<BH;++j){
        float w1a=bW1[j], w1b=bW1[BH+j], b1=bb1[j];
        float hd = fmaxf(di*w1a + dj*w1b + b1, 0.f);
        float4 wa=*(const float4*)(bW2 + j*HH);
        float4 wb=*(const float4*)(bW2 + j*HH + 4);
        o0+=hd*wa.x; o1+=hd*wa.y; o2+=hd*wa.z; o3+=hd*wa.w;
        o4+=hd*wb.x; o5+=hd*wb.y; o6+=hd*wb.z; o7+=hd*wb.w;
      }
      float* bp = biasO + ((size_t)((size_t)b*NN+n)*NC + c)*HH;
      bp[0]=o0+z0.x; bp[1]=o1+z0.y; bp[2]=o2+z0.z; bp[3]=o3+z0.w;
      bp[4]=o4+z1.x; bp[5]=o5+z1.y; bp[6]=o6+z1.z; bp[7]=o7+z1.w;
    }
  }
}

// prep2: 512 threads, 3 barriers. x2 (wave per candidate), K5/V5 (d-split),
// U5/eU5/W5 (h-split across waves).
__global__ __launch_bounds__(512) void prep2_kernel(
  const float* __restrict__ tokens,
  const float* __restrict__ ln2_g, const float* __restrict__ ln2_b,
  const float* __restrict__ pWqT, const float* __restrict__ eWqT,
  const float* __restrict__ pWk, const float* __restrict__ pWv,
  const float* __restrict__ pWo,
  const float* __restrict__ v2g, const int* __restrict__ candI,
  float* __restrict__ U5, float* __restrict__ eU5, float* __restrict__ W5)
{
  __shared__ float sX2[NC][DD];
  __shared__ float sPK[2][NC][DD];
  __shared__ float sPV[2][NC][DD];
  __shared__ float sK5[NC][DD];
  __shared__ float sV5[NC][DD];
  int b = blockIdx.x, t = threadIdx.x;
  int lane = t & 63, wave = t >> 6;

  // ---- phase 1: x2 for the 5 candidates, one wave each (wave-local LN) ----
  if (wave < NC){
    int ci = candI[b*8+wave];
    float4 tk = *(const float4*)(tokens + ((size_t)b*NN+ci)*DD + 4*lane);
    float4 v2 = *(const float4*)(v2g + (size_t)b*DD + 4*lane);
    float h0=tk.x+v2.x, h1=tk.y+v2.y, h2=tk.z+v2.z, h3=tk.w+v2.w;
    float s1=h0+h1+h2+h3, s2=h0*h0+h1*h1+h2*h2+h3*h3;
    #pragma unroll
    for (int m=32;m>=1;m>>=1){ s1+=__shfl_xor(s1,m); s2+=__shfl_xor(s2,m); }
    float mu = s1*(1.0f/DD), var = s2*(1.0f/DD)-mu*mu;
    float rs = rsqrtf(var+1e-5f);
    float4 g = *(const float4*)(ln2_g + 4*lane);
    float4 bb = *(const float4*)(ln2_b + 4*lane);
    *(float4*)(&sX2[wave][4*lane]) = make_float4(
      (h0-mu)*rs*g.x+bb.x, (h1-mu)*rs*g.y+bb.y,
      (h2-mu)*rs*g.z+bb.z, (h3-mu)*rs*g.w+bb.w);
  }
  __syncthreads();
  // ---- phase 2: K5/V5 partials, d-loop split in half ----
  {
    int tt = t & 255, half = t >> 8;
    float k0=0,k1=0,k2=0,k3=0,k4=0, v0=0,v1=0,v2=0,v3=0,v4=0;
    #pragma unroll 2
    for (int dd=0; dd<128; ++dd){
      int d = half*128 + dd;
      float wk = pWk[(size_t)d*DD + tt];
      float wv = pWv[(size_t)d*DD + tt];
      float xa=sX2[0][d], xb=sX2[1][d], xc=sX2[2][d], xd=sX2[3][d], xe2=sX2[4][d];
      k0+=xa*wk; k1+=xb*wk; k2+=xc*wk; k3+=xd*wk; k4+=xe2*wk;
      v0+=xa*wv; v1+=xb*wv; v2+=xc*wv; v3+=xd*wv; v4+=xe2*wv;
    }
    sPK[half][0][tt]=k0; sPK[half][1][tt]=k1; sPK[half][2][tt]=k2;
    sPK[half][3][tt]=k3; sPK[half][4][tt]=k4;
    sPV[half][0][tt]=v0; sPV[half][1][tt]=v1; sPV[half][2][tt]=v2;
    sPV[half][3][tt]=v3; sPV[half][4][tt]=v4;
  }
  __syncthreads();
  // ---- phase 3: combine halves ----
  if (t < 256){
    #pragma unroll
    for (int c=0;c<NC;++c) sK5[c][t] = sPK[0][c][t] + sPK[1][c][t];
  } else {
    int tt = t-256;
    #pragma unroll
    for (int c=0;c<NC;++c) sV5[c][tt] = sPV[0][c][tt] + sPV[1][c][tt];
  }
  __syncthreads();
  // ---- phase 4: U5/eU5 then W5, h = wave ----
  {
    int h = wave;
    float ua[NC][4], ea[NC][4];
    #pragma unroll
    for (int c=0;c<NC;++c){
      #pragma unroll
      for (int j=0;j<4;++j){ ua[c][j]=0.f; ea[c][j]=0.f; }
    }
    #pragma unroll 4
    for (int dd=0; dd<32; ++dd){
      int d = h*32+dd;
      float k0=sK5[0][d], k1=sK5[1][d], k2=sK5[2][d], k3=sK5[3][d], k4=sK5[4][d];
      #pragma unroll
      for (int j=0;j<4;++j){
        float wq = pWqT[(size_t)d*DD + lane + 64*j];
        float we = eWqT[(size_t)d*DD + lane + 64*j];
        ua[0][j]+=wq*k0; ua[1][j]+=wq*k1; ua[2][j]+=wq*k2; ua[3][j]+=wq*k3; ua[4][j]+=wq*k4;
        ea[0][j]+=we*k0; ea[1][j]+=we*k1; ea[2][j]+=we*k2; ea[3][j]+=we*k3; ea[4][j]+=we*k4;
      }
    }
    size_t ub = (size_t)b*NC*HH*DD + (size_t)h*DD + lane;
    #pragma unroll
    for (int c=0;c<NC;++c){
      #pragma unroll
      for (int j=0;j<4;++j){
        U5 [ub + (size_t)c*HH*DD + 64*j] = ua[c][j]*SCALE_INV;
        eU5[ub + (size_t)c*HH*DD + 64*j] = ea[c][j]*SCALE_INV;
      }
    }
    float wa[NC][4];
    #pragma unroll
    for (int c=0;c<NC;++c){
      #pragma unroll
      for (int j=0;j<4;++j) wa[c][j]=0.f;
    }
    #pragma unroll 4
    for (int dd=0; dd<32; ++dd){
      int d = h*32+dd;
      float v0=sV5[0][d], v1=sV5[1][d], v2=sV5[2][d], v3=sV5[3][d], v4=sV5[4][d];
      #pragma unroll
      for (int j=0;j<4;++j){
        float wo = pWo[(size_t)d*DD + lane + 64*j];
        wa[0][j]+=wo*v0; wa[1][j]+=wo*v1; wa[2][j]+=wo*v2; wa[3][j]+=wo*v3; wa[4][j]+=wo*v4;
      }
    }
    #pragma unroll
    for (int c=0;c<NC;++c){
      #pragma unroll
      for (int j=0;j<4;++j)
        W5[ub + (size_t)c*HH*DD + 64*j] = wa[c][j];
    }
  }
}

// 8 named partials (one per h) -> lane holds full sum for h=lane>>3.
__device__ __forceinline__ float reduce40(
  float q0,float q1,float q2,float q3,float q4,float q5,float q6,float q7,int lane)
{
  const bool b5 = (lane&32)!=0, b4 = (lane&16)!=0, b3 = (lane&8)!=0;
  float r0 = (b5? q4:q0) + __shfl_xor(b5? q0:q4, 32);
  float r1 = (b5? q5:q1) + __shfl_xor(b5? q1:q5, 32);
  float r2 = (b5? q6:q2) + __shfl_xor(b5? q2:q6, 32);
  float r3 = (b5? q7:q3) + __shfl_xor(b5? q3:q7, 32);
  float t0 = (b4? r2:r0) + __shfl_xor(b4? r0:r2, 16);
  float t1 = (b4? r3:r1) + __shfl_xor(b4? r1:r3, 16);
  float s  = (b3? t1:t0) + __shfl_xor(b3? t0:t1, 8);
  s += __shfl_xor(s,4); s += __shfl_xor(s,2); s += __shfl_xor(s,1);
  return s;
}

// one candidate-block score for one row from a global/LDS base
__device__ __forceinline__ float dotred(const float* base, float xa, float xb,
                                        float xc, float xd, int lane)
{
  const float* ub = base + 4*lane;
  float4 u;
  u=*(const float4*)(ub+0*DD); float q0=xa*u.x+xb*u.y+xc*u.z+xd*u.w;
  u=*(const float4*)(ub+1*DD); float q1=xa*u.x+xb*u.y+xc*u.z+xd*u.w;
  u=*(const float4*)(ub+2*DD); float q2=xa*u.x+xb*u.y+xc*u.z+xd*u.w;
  u=*(const float4*)(ub+3*DD); float q3=xa*u.x+xb*u.y+xc*u.z+xd*u.w;
  u=*(const float4*)(ub+4*DD); float q4=xa*u.x+xb*u.y+xc*u.z+xd*u.w;
  u=*(const float4*)(ub+5*DD); float q5=xa*u.x+xb*u.y+xc*u.z+xd*u.w;
  u=*(const float4*)(ub+6*DD); float q6=xa*u.x+xb*u.y+xc*u.z+xd*u.w;
  u=*(const float4*)(ub+7*DD); float q7=xa*u.x+xb*u.y+xc*u.z+xd*u.w;
  return reduce40(q0,q1,q2,q3,q4,q5,q6,q7,lane);
}

// One block per batch, 512 threads = 8 waves. Each wave: 8 iterations of a
// 2-row pair (n, n+64) so every U5/W5 ds_read feeds 2 rows. Named scalars
// only; fits 128-VGPR cap of (512,4).
__global__ __launch_bounds__(512, 4) void main_kernel(
  const float* __restrict__ tokens, const int* __restrict__ ego_idx,
  const float* __restrict__ v2g, const int* __restrict__ candI,
  const float* __restrict__ U5g, const float* __restrict__ eU5g,
  const float* __restrict__ W5g, const float* __restrict__ biasO,
  const float* __restrict__ ln2_g, const float* __restrict__ ln2_b,
  float* __restrict__ out)
{
  __shared__ float sU[NC*HH*DD];
  __shared__ float sW[NC*HH*DD];
  int b = blockIdx.x, t = threadIdx.x;
  int lane = t & 63, wave = t >> 6;
  {
    const float4* srcU = (const float4*)(U5g + (size_t)b*NC*HH*DD);
    const float4* srcW = (const float4*)(W5g + (size_t)b*NC*HH*DD);
    float4* dU = (float4*)sU; float4* dW = (float4*)sW;
    #pragma unroll
    for (int i=0;i<5;++i){ dU[t+512*i]=srcU[t+512*i]; dW[t+512*i]=srcW[t+512*i]; }
  }
  int ego = ego_idx[b];
  const int* cip = candI + b*8;
  int ci0=cip[0],ci1=cip[1],ci2=cip[2],ci3=cip[3],ci4=cip[4];
  float4 v2r = *(const float4*)(v2g + (size_t)b*DD + 4*lane);
  float4 g4  = *(const float4*)(ln2_g + 4*lane);
  float4 b4  = *(const float4*)(ln2_b + 4*lane);
  int h_lane = lane>>3;
  __syncthreads();

  for (int g=0; g<8; ++g){
    int nA = wave + 8*g, nB = nA + 64;
    float4 tA = *(const float4*)(tokens + ((size_t)b*NN+nA)*DD + 4*lane);
    float4 tB = *(const float4*)(tokens + ((size_t)b*NN+nB)*DD + 4*lane);
    const float* bpA = biasO + ((size_t)b*NN+nA)*NC*HH + h_lane;
    const float* bpB = biasO + ((size_t)b*NN+nB)*NC*HH + h_lane;
    float biA0=bpA[0], biA1=bpA[8], biA2=bpA[16], biA3=bpA[24], biA4=bpA[32];
    float biB0=bpB[0], biB1=bpB[8], biB2=bpB[16], biB3=bpB[24], biB4=bpB[32];
    float hA0=tA.x+v2r.x, hA1=tA.y+v2r.y, hA2=tA.z+v2r.z, hA3=tA.w+v2r.w;
    float hB0=tB.x+v2r.x, hB1=tB.y+v2r.y, hB2=tB.z+v2r.z, hB3=tB.w+v2r.w;
    float s1A=hA0+hA1+hA2+hA3, s2A=hA0*hA0+hA1*hA1+hA2*hA2+hA3*hA3;
    float s1B=hB0+hB1+hB2+hB3, s2B=hB0*hB0+hB1*hB1+hB2*hB2+hB3*hB3;
    #pragma unroll
    for (int m=32;m>=1;m>>=1){
      s1A+=__shfl_xor(s1A,m); s2A+=__shfl_xor(s2A,m);
      s1B+=__shfl_xor(s1B,m); s2B+=__shfl_xor(s2B,m);
    }
    float muA=s1A*(1.0f/DD), varA=s2A*(1.0f/DD)-muA*muA, rsA=rsqrtf(varA+1e-5f);
    float muB=s1B*(1.0f/DD), varB=s2B*(1.0f/DD)-muB*muB, rsB=rsqrtf(varB+1e-5f);
    float xA0=(hA0-muA)*rsA*g4.x+b4.x, xA1=(hA1-muA)*rsA*g4.y+b4.y;
    float xA2=(hA2-muA)*rsA*g4.z+b4.z, xA3=(hA3-muA)*rsA*g4.w+b4.w;
    float xB0=(hB0-muB)*rsB*g4.x+b4.x, xB1=(hB1-muB)*rsB*g4.y+b4.y;
    float xB2=(hB2-muB)*rsB*g4.z+b4.z, xB3=(hB3-muB)*rsB*g4.w+b4.w;
    float scA0,scA1,scA2,scA3,scA4, scB0,scB1,scB2,scB3,scB4;
#define DOT8P(BASE, RA, RB) { \
    const float* ub_ = (BASE) + 4*lane; float4 u_; \
    float qA0,qA1,qA2,qA3,qA4,qA5,qA6,qA7, qB0,qB1,qB2,qB3,qB4,qB5,qB6,qB7; \
    u_=*(const float4*)(ub_+0*DD); qA0=xA0*u_.x+xA1*u_.y+xA2*u_.z+xA3*u_.w; qB0=xB0*u_.x+xB1*u_.y+xB2*u_.z+xB3*u_.w; \
    u_=*(const float4*)(ub_+1*DD); qA1=xA0*u_.x+xA1*u_.y+xA2*u_.z+xA3*u_.w; qB1=xB0*u_.x+xB1*u_.y+xB2*u_.z+xB3*u_.w; \
    u_=*(const float4*)(ub_+2*DD); qA2=xA0*u_.x+xA1*u_.y+xA2*u_.z+xA3*u_.w; qB2=xB0*u_.x+xB1*u_.y+xB2*u_.z+xB3*u_.w; \
    u_=*(const float4*)(ub_+3*DD); qA3=xA0*u_.x+xA1*u_.y+xA2*u_.z+xA3*u_.w; qB3=xB0*u_.x+xB1*u_.y+xB2*u_.z+xB3*u_.w; \
    u_=*(const float4*)(ub_+4*DD); qA4=xA0*u_.x+xA1*u_.y+xA2*u_.z+xA3*u_.w; qB4=xB0*u_.x+xB1*u_.y+xB2*u_.z+xB3*u_.w; \
    u_=*(const float4*)(ub_+5*DD); qA5=xA0*u_.x+xA1*u_.y+xA2*u_.z+xA3*u_.w; qB5=xB0*u_.x+xB1*u_.y+xB2*u_.z+xB3*u_.w; \
    u_=*(const float4*)(ub_+6*DD); qA6=xA0*u_.x+xA1*u_.y+xA2*u_.z+xA3*u_.w; qB6=xB0*u_.x+xB1*u_.y+xB2*u_.z+xB3*u_.w; \
    u_=*(const float4*)(ub_+7*DD); qA7=xA0*u_.x+xA1*u_.y+xA2*u_.z+xA3*u_.w; qB7=xB0*u_.x+xB1*u_.y+xB2*u_.z+xB3*u_.w; \
    RA = reduce40(qA0,qA1,qA2,qA3,qA4,qA5,qA6,qA7,lane); \
    RB = reduce40(qB0,qB1,qB2,qB3,qB4,qB5,qB6,qB7,lane); }
    DOT8P(sU + 0*HH*DD, scA0, scB0)
    DOT8P(sU + 1*HH*DD, scA1, scB1)
    DOT8P(sU + 2*HH*DD, scA2, scB2)
    DOT8P(sU + 3*HH*DD, scA3, scB3)
    DOT8P(sU + 4*HH*DD, scA4, scB4)
#undef DOT8P
    if (nA==ego){
      const float* eb = eU5g + (size_t)b*NC*HH*DD;
      scA0 = dotred(eb+0*HH*DD, xA0,xA1,xA2,xA3, lane);
      scA1 = dotred(eb+1*HH*DD, xA0,xA1,xA2,xA3, lane);
      scA2 = dotred(eb+2*HH*DD, xA0,xA1,xA2,xA3, lane);
      scA3 = dotred(eb+3*HH*DD, xA0,xA1,xA2,xA3, lane);
      scA4 = dotred(eb+4*HH*DD, xA0,xA1,xA2,xA3, lane);
    }
    if (nB==ego){
      const float* eb = eU5g + (size_t)b*NC*HH*DD;
      scB0 = dotred(eb+0*HH*DD, xB0,xB1,xB2,xB3, lane);
      scB1 = dotred(eb+1*HH*DD, xB0,xB1,xB2,xB3, lane);
      scB2 = dotred(eb+2*HH*DD, xB0,xB1,xB2,xB3, lane);
      scB3 = dotred(eb+3*HH*DD, xB0,xB1,xB2,xB3, lane);
      scB4 = dotred(eb+4*HH*DD, xB0,xB1,xB2,xB3, lane);
    }
    // ---- mask + softmax row A ----
    {
      int pos = (ci0==nA)?0:(ci1==nA)?1:(ci2==nA)?2:(ci3==nA)?3:(ci4==nA)?4:5;
      int bad = (pos==5)?4:pos;
      scA0 = (bad==0)? -1e30f : scA0+biA0;
      scA1 = (bad==1)? -1e30f : scA1+biA1;
      scA2 = (bad==2)? -1e30f : scA2+biA2;
      scA3 = (bad==3)? -1e30f : scA3+biA3;
      scA4 = (bad==4)? -1e30f : scA4+biA4;
      float mx = fmaxf(fmaxf(fmaxf(scA0,scA1),fmaxf(scA2,scA3)),scA4);
      float e0=__expf(scA0-mx), e1=__expf(scA1-mx), e2=__expf(scA2-mx);
      float e3=__expf(scA3-mx), e4=__expf(scA4-mx);
      float inv = 1.0f/(e0+e1+e2+e3+e4);
      scA0=e0*inv; scA1=e1*inv; scA2=e2*inv; scA3=e3*inv; scA4=e4*inv;
    }
    // ---- mask + softmax row B ----
    {
      int pos = (ci0==nB)?0:(ci1==nB)?1:(ci2==nB)?2:(ci3==nB)?3:(ci4==nB)?4:5;
      int bad = (pos==5)?4:pos;
      scB0 = (bad==0)? -1e30f : scB0+biB0;
      scB1 = (bad==1)? -1e30f : scB1+biB1;
      scB2 = (bad==2)? -1e30f : scB2+biB2;
      scB3 = (bad==3)? -1e30f : scB3+biB3;
      scB4 = (bad==4)? -1e30f : scB4+biB4;
      float mx = fmaxf(fmaxf(fmaxf(scB0,scB1),fmaxf(scB2,scB3)),scB4);
      float e0=__expf(scB0-mx), e1=__expf(scB1-mx), e2=__expf(scB2-mx);
      float e3=__expf(scB3-mx), e4=__expf(scB4-mx);
      float inv = 1.0f/(e0+e1+e2+e3+e4);
      scB0=e0*inv; scB1=e1*inv; scB2=e2*inv; scB3=e3*inv; scB4=e4*inv;
    }
    // ---- output: each W5 read feeds both rows ----
    float oA0=0,oA1=0,oA2=0,oA3=0, oB0=0,oB1=0,oB2=0,oB3=0;
    #pragma unroll
    for (int c=0;c<NC;++c){
      float wcA = (c==0)?scA0:(c==1)?scA1:(c==2)?scA2:(c==3)?scA3:scA4;
      float wcB = (c==0)?scB0:(c==1)?scB1:(c==2)?scB2:(c==3)?scB3:scB4;
      #pragma unroll
      for (int h=0;h<HH;++h){
        const float4 wr = *(const float4*)(sW + (c*HH+h)*DD + 4*lane);
        float wvA = __shfl(wcA, h*8);
        float wvB = __shfl(wcB, h*8);
        oA0+=wvA*wr.x; oA1+=wvA*wr.y; oA2+=wvA*wr.z; oA3+=wvA*wr.w;
        oB0+=wvB*wr.x; oB1+=wvB*wr.y; oB2+=wvB*wr.z; oB3+=wvB*wr.w;
      }
    }
    *(float4*)(out + ((size_t)b*NN+nA)*DD + 4*lane) =
        make_float4(hA0+oA0, hA1+oA1, hA2+oA2, hA3+oA3);
    *(float4*)(out + ((size_t)b*NN+nB)*DD + 4*lane) =
        make_float4(hB0+oB0, hB1+oB1, hB2+oB2, hB3+oB3);
  }
}

extern "C" void kernel_launch(void* const* d_in, const int* in_sizes, int n_in,
                              void* d_out, int out_size, void* d_ws, size_t ws_size,
                              hipStream_t stream) {
  (void)in_sizes; (void)n_in; (void)out_size; (void)ws_size;
  const float* tokens = (const float*)d_in[0];
  const int*   ego_idx= (const int*)  d_in[1];
  const float* dist   = (const float*)d_in[2];
  // d_in[3] = ego_speed (unused by reference)
  const float* ln1_g  = (const float*)d_in[4];
  const float* ln1_b  = (const float*)d_in[5];
  const float* ln2_g  = (const float*)d_in[6];
  const float* ln2_b  = (const float*)d_in[7];
  // d_in[8]=cWq, d_in[9]=cWk dead: softmax over singleton axis == 1
  const float* cWv    = (const float*)d_in[10];
  const float* cWo    = (const float*)d_in[11];
  const float* pWq    = (const float*)d_in[12];
  const float* eWq    = (const float*)d_in[13];
  const float* pWk    = (const float*)d_in[14];
  const float* pWv    = (const float*)d_in[15];
  const float* pWo    = (const float*)d_in[16];
  const float* bW1    = (const float*)d_in[17];
  const float* bb1    = (const float*)d_in[18];
  const float* bW2    = (const float*)d_in[19];
  const float* bb2    = (const float*)d_in[20];
  float* outp = (float*)d_out;

  char* w = (char*)d_ws;
  float* v2g   = (float*)w; w += (size_t)BB*DD*4;
  int*   candI = (int*)w;   w += (size_t)BB*8*4;
  float* U5    = (float*)w; w += (size_t)BB*NC*HH*DD*4;
  float* eU5   = (float*)w; w += (size_t)BB*NC*HH*DD*4;
  float* W5    = (float*)w; w += (size_t)BB*NC*HH*DD*4;
  float* biasO = (float*)w; w += (size_t)BB*NN*NC*HH*4;
  float* pWqT  = (float*)w; w += (size_t)DD*DD*4;
  float* eWqT  = (float*)w; w += (size_t)DD*DD*4;

  transpose_kernel<<<dim3(8,8,2), dim3(256), 0, stream>>>(pWq, eWq, pWqT, eWqT);

  prep1_kernel<<<dim3(BB), dim3(512), 0, stream>>>(
      tokens, ego_idx, dist, ln1_g, ln1_b, cWv, cWo,
      bW1, bb1, bW2, bb2, v2g, candI, biasO);

  prep2_kernel<<<dim3(BB), dim3(512), 0, stream>>>(
      tokens, ln2_g, ln2_b, pWqT, eWqT, pWk, pWv, pWo,
      v2g, candI, U5, eU5, W5);

  main_kernel<<<dim3(BB), dim3(512), 0, stream>>>(
      tokens, ego_idx, v2g, candI, U5, eU5, W5, biasO, ln2_g, ln2_b, outp);
}

// Round 8
// 626.008 us; speedup vs baseline: 1.6894x; 1.6894x over previous
//
#include <hip/hip_runtime.h>
#include <math.h>

#define BB 512
#define NN 128
#define DD 256
#define HH 8
#define NC 5
#define BH 64
#define SCALE_INV 0.17677669529663687f  // 1/sqrt(32)

// One-shot transpose of pWq and eWq (256x256 each) so prep2's U5 loop reads
// them coalesced.
__global__ __launch_bounds__(256) void transpose_kernel(
  const float* __restrict__ A, const float* __restrict__ B,
  float* __restrict__ AT, float* __restrict__ BT)
{
  __shared__ float tile[32][33];
  int bx = blockIdx.x, by = blockIdx.y, z = blockIdx.z;
  const float* src = z ? B : A;
  float* dst = z ? BT : AT;
  int tx = threadIdx.x & 31, ty = threadIdx.x >> 5;
  #pragma unroll
  for (int k=0;k<4;++k)
    tile[ty+8*k][tx] = src[(size_t)(by*32+ty+8*k)*DD + bx*32+tx];
  __syncthreads();
  #pragma unroll
  for (int k=0;k<4;++k)
    dst[(size_t)(bx*32+ty+8*k)*DD + by*32+tx] = tile[tx][ty+8*k];
}

// prep1: 512 threads, NO barriers. Wave 0: LN1->Ve->v2 (wave-local chain).
// Waves 1-7: redundant wave-local top-5, then disjoint bias-table slices.
__global__ __launch_bounds__(512) void prep1_kernel(
  const float* __restrict__ tokens, const int* __restrict__ ego_idx,
  const float* __restrict__ dist,
  const float* __restrict__ ln1_g, const float* __restrict__ ln1_b,
  const float* __restrict__ cWv, const float* __restrict__ cWo,
  const float* __restrict__ bW1, const float* __restrict__ bb1,
  const float* __restrict__ bW2, const float* __restrict__ bb2,
  float* __restrict__ v2g, int* __restrict__ candI,
  float* __restrict__ biasO)
{
  int b = blockIdx.x, t = threadIdx.x;
  int lane = t & 63, wave = t >> 6;
  int ego = ego_idx[b];

  if (wave == 0){
    // ---- LN1(ego): x1 distributed 4 elems/lane ----
    float4 xe = *(const float4*)(tokens + ((size_t)b*NN+ego)*DD + 4*lane);
    float s1 = xe.x+xe.y+xe.z+xe.w;
    float s2 = xe.x*xe.x+xe.y*xe.y+xe.z*xe.z+xe.w*xe.w;
    #pragma unroll
    for (int m=32;m>=1;m>>=1){ s1+=__shfl_xor(s1,m); s2+=__shfl_xor(s2,m); }
    float mu = s1*(1.0f/DD), var = s2*(1.0f/DD)-mu*mu;
    float rs = rsqrtf(var+1e-5f);
    float4 g = *(const float4*)(ln1_g + 4*lane);
    float4 bb = *(const float4*)(ln1_b + 4*lane);
    float x10=(xe.x-mu)*rs*g.x+bb.x;
    float x11=(xe.y-mu)*rs*g.y+bb.y;
    float x12=(xe.z-mu)*rs*g.z+bb.z;
    float x13=(xe.w-mu)*rs*g.w+bb.w;
    // ---- Ve[t]=sum_d x1[d]*cWv[d][t], t=4*lane+j ----
    float a0=0,a1=0,a2=0,a3=0;
    #pragma unroll 2
    for (int d0=0; d0<DD; d0+=4){
      int src = d0>>2;
      float c0=__shfl(x10,src), c1=__shfl(x11,src), c2=__shfl(x12,src), c3=__shfl(x13,src);
      float4 w0=*(const float4*)(cWv + (size_t)(d0  )*DD + 4*lane);
      float4 w1=*(const float4*)(cWv + (size_t)(d0+1)*DD + 4*lane);
      float4 w2=*(const float4*)(cWv + (size_t)(d0+2)*DD + 4*lane);
      float4 w3=*(const float4*)(cWv + (size_t)(d0+3)*DD + 4*lane);
      a0 += c0*w0.x + c1*w1.x + c2*w2.x + c3*w3.x;
      a1 += c0*w0.y + c1*w1.y + c2*w2.y + c3*w3.y;
      a2 += c0*w0.z + c1*w1.z + c2*w2.z + c3*w3.z;
      a3 += c0*w0.w + c1*w1.w + c2*w2.w + c3*w3.w;
    }
    // ---- v2 = Ve @ cWo ----
    float e0=0,e1=0,e2=0,e3=0;
    #pragma unroll 2
    for (int d0=0; d0<DD; d0+=4){
      int src = d0>>2;
      float c0=__shfl(a0,src), c1=__shfl(a1,src), c2=__shfl(a2,src), c3=__shfl(a3,src);
      float4 w0=*(const float4*)(cWo + (size_t)(d0  )*DD + 4*lane);
      float4 w1=*(const float4*)(cWo + (size_t)(d0+1)*DD + 4*lane);
      float4 w2=*(const float4*)(cWo + (size_t)(d0+2)*DD + 4*lane);
      float4 w3=*(const float4*)(cWo + (size_t)(d0+3)*DD + 4*lane);
      e0 += c0*w0.x + c1*w1.x + c2*w2.x + c3*w3.x;
      e1 += c0*w0.y + c1*w1.y + c2*w2.y + c3*w3.y;
      e2 += c0*w0.z + c1*w1.z + c2*w2.z + c3*w3.z;
      e3 += c0*w0.w + c1*w1.w + c2*w2.w + c3*w3.w;
    }
    *(float4*)(v2g + (size_t)b*DD + 4*lane) = make_float4(e0,e1,e2,e3);
  } else {
    // ---- wave-local top-5 (redundant per wave) ----
    unsigned long long kk0 = (((unsigned long long)__float_as_uint(dist[b*NN+lane]))<<32) | (unsigned)lane;
    unsigned long long kk1 = (((unsigned long long)__float_as_uint(dist[b*NN+lane+64]))<<32) | (unsigned)(lane+64);
    int ci0,ci1,ci2,ci3,ci4; float cd0,cd1,cd2,cd3,cd4;
    #define TOP5ROUND(CI,CD) { \
      unsigned long long m_ = kk0<kk1?kk0:kk1; \
      _Pragma("unroll") \
      for (int s_=32;s_>=1;s_>>=1){ unsigned long long o_=__shfl_xor(m_,s_); if(o_<m_)m_=o_; } \
      CI = (int)(m_ & 0xffffffffULL); CD = __uint_as_float((unsigned)(m_>>32)); \
      if (CI==lane) kk0=~0ULL; if (CI==lane+64) kk1=~0ULL; }
    TOP5ROUND(ci0,cd0)
    TOP5ROUND(ci1,cd1)
    TOP5ROUND(ci2,cd2)
    TOP5ROUND(ci3,cd3)
    TOP5ROUND(ci4,cd4)
    #undef TOP5ROUND
    if (wave==1 && lane==0){
      candI[b*8+0]=ci0; candI[b*8+1]=ci1; candI[b*8+2]=ci2;
      candI[b*8+3]=ci3; candI[b*8+4]=ci4;
    }
    // ---- bias table slices: 640 outputs over waves 1-7, two rounds ----
    float4 z0 = *(const float4*)(bb2);
    float4 z1 = *(const float4*)(bb2+4);
    #pragma unroll 1
    for (int rnd=0; rnd<2; ++rnd){
      int p = (rnd==0) ? (wave-1)*64 + lane : 448 + (wave-1)*64 + lane;
      if (p >= NN*NC) continue;     // wave-uniform skip in round 1
      unsigned n = (unsigned)p / NC;
      int c = p - (int)n*NC;
      float dj = (c==0)?cd0:(c==1)?cd1:(c==2)?cd2:(c==3)?cd3:cd4;
      float di = dist[b*NN + n];
      float o0=0,o1=0,o2=0,o3=0,o4=0,o5=0,o6=0,o7=0;
      #pragma unroll 4
      for (int j=0;j<BH;++j){
        float w1a=bW1[j], w1b=bW1[BH+j], b1=bb1[j];
        float hd = fmaxf(di*w1a + dj*w1b + b1, 0.f);
        float4 wa=*(const float4*)(bW2 + j*HH);
        float4 wb=*(const float4*)(bW2 + j*HH + 4);
        o0+=hd*wa.x; o1+=hd*wa.y; o2+=hd*wa.z; o3+=hd*wa.w;
        o4+=hd*wb.x; o5+=hd*wb.y; o6+=hd*wb.z; o7+=hd*wb.w;
      }
      float* bp = biasO + ((size_t)((size_t)b*NN+n)*NC + c)*HH;
      bp[0]=o0+z0.x; bp[1]=o1+z0.y; bp[2]=o2+z0.z; bp[3]=o3+z0.w;
      bp[4]=o4+z1.x; bp[5]=o5+z1.y; bp[6]=o6+z1.z; bp[7]=o7+z1.w;
    }
  }
}

// prep2: 512 threads, 3 barriers. x2 (wave per candidate), K5/V5 (d-split),
// U5/eU5/W5 (h-split across waves).
__global__ __launch_bounds__(512) void prep2_kernel(
  const float* __restrict__ tokens,
  const float* __restrict__ ln2_g, const float* __restrict__ ln2_b,
  const float* __restrict__ pWqT, const float* __restrict__ eWqT,
  const float* __restrict__ pWk, const float* __restrict__ pWv,
  const float* __restrict__ pWo,
  const float* __restrict__ v2g, const int* __restrict__ candI,
  float* __restrict__ U5, float* __restrict__ eU5, float* __restrict__ W5)
{
  __shared__ float sX2[NC][DD];
  __shared__ float sPK[2][NC][DD];
  __shared__ float sPV[2][NC][DD];
  __shared__ float sK5[NC][DD];
  __shared__ float sV5[NC][DD];
  int b = blockIdx.x, t = threadIdx.x;
  int lane = t & 63, wave = t >> 6;

  // ---- phase 1: x2 for the 5 candidates, one wave each (wave-local LN) ----
  if (wave < NC){
    int ci = candI[b*8+wave];
    float4 tk = *(const float4*)(tokens + ((size_t)b*NN+ci)*DD + 4*lane);
    float4 v2 = *(const float4*)(v2g + (size_t)b*DD + 4*lane);
    float h0=tk.x+v2.x, h1=tk.y+v2.y, h2=tk.z+v2.z, h3=tk.w+v2.w;
    float s1=h0+h1+h2+h3, s2=h0*h0+h1*h1+h2*h2+h3*h3;
    #pragma unroll
    for (int m=32;m>=1;m>>=1){ s1+=__shfl_xor(s1,m); s2+=__shfl_xor(s2,m); }
    float mu = s1*(1.0f/DD), var = s2*(1.0f/DD)-mu*mu;
    float rs = rsqrtf(var+1e-5f);
    float4 g = *(const float4*)(ln2_g + 4*lane);
    float4 bb = *(const float4*)(ln2_b + 4*lane);
    *(float4*)(&sX2[wave][4*lane]) = make_float4(
      (h0-mu)*rs*g.x+bb.x, (h1-mu)*rs*g.y+bb.y,
      (h2-mu)*rs*g.z+bb.z, (h3-mu)*rs*g.w+bb.w);
  }
  __syncthreads();
  // ---- phase 2: K5/V5 partials, d-loop split in half ----
  {
    int tt = t & 255, half = t >> 8;
    float k0=0,k1=0,k2=0,k3=0,k4=0, v0=0,v1=0,v2=0,v3=0,v4=0;
    #pragma unroll 2
    for (int dd=0; dd<128; ++dd){
      int d = half*128 + dd;
      float wk = pWk[(size_t)d*DD + tt];
      float wv = pWv[(size_t)d*DD + tt];
      float xa=sX2[0][d], xb=sX2[1][d], xc=sX2[2][d], xd=sX2[3][d], xe2=sX2[4][d];
      k0+=xa*wk; k1+=xb*wk; k2+=xc*wk; k3+=xd*wk; k4+=xe2*wk;
      v0+=xa*wv; v1+=xb*wv; v2+=xc*wv; v3+=xd*wv; v4+=xe2*wv;
    }
    sPK[half][0][tt]=k0; sPK[half][1][tt]=k1; sPK[half][2][tt]=k2;
    sPK[half][3][tt]=k3; sPK[half][4][tt]=k4;
    sPV[half][0][tt]=v0; sPV[half][1][tt]=v1; sPV[half][2][tt]=v2;
    sPV[half][3][tt]=v3; sPV[half][4][tt]=v4;
  }
  __syncthreads();
  // ---- phase 3: combine halves ----
  if (t < 256){
    #pragma unroll
    for (int c=0;c<NC;++c) sK5[c][t] = sPK[0][c][t] + sPK[1][c][t];
  } else {
    int tt = t-256;
    #pragma unroll
    for (int c=0;c<NC;++c) sV5[c][tt] = sPV[0][c][tt] + sPV[1][c][tt];
  }
  __syncthreads();
  // ---- phase 4: U5/eU5 then W5, h = wave ----
  {
    int h = wave;
    float ua[NC][4], ea[NC][4];
    #pragma unroll
    for (int c=0;c<NC;++c){
      #pragma unroll
      for (int j=0;j<4;++j){ ua[c][j]=0.f; ea[c][j]=0.f; }
    }
    #pragma unroll 4
    for (int dd=0; dd<32; ++dd){
      int d = h*32+dd;
      float k0=sK5[0][d], k1=sK5[1][d], k2=sK5[2][d], k3=sK5[3][d], k4=sK5[4][d];
      #pragma unroll
      for (int j=0;j<4;++j){
        float wq = pWqT[(size_t)d*DD + lane + 64*j];
        float we = eWqT[(size_t)d*DD + lane + 64*j];
        ua[0][j]+=wq*k0; ua[1][j]+=wq*k1; ua[2][j]+=wq*k2; ua[3][j]+=wq*k3; ua[4][j]+=wq*k4;
        ea[0][j]+=we*k0; ea[1][j]+=we*k1; ea[2][j]+=we*k2; ea[3][j]+=we*k3; ea[4][j]+=we*k4;
      }
    }
    size_t ub = (size_t)b*NC*HH*DD + (size_t)h*DD + lane;
    #pragma unroll
    for (int c=0;c<NC;++c){
      #pragma unroll
      for (int j=0;j<4;++j){
        U5 [ub + (size_t)c*HH*DD + 64*j] = ua[c][j]*SCALE_INV;
        eU5[ub + (size_t)c*HH*DD + 64*j] = ea[c][j]*SCALE_INV;
      }
    }
    float wa[NC][4];
    #pragma unroll
    for (int c=0;c<NC;++c){
      #pragma unroll
      for (int j=0;j<4;++j) wa[c][j]=0.f;
    }
    #pragma unroll 4
    for (int dd=0; dd<32; ++dd){
      int d = h*32+dd;
      float v0=sV5[0][d], v1=sV5[1][d], v2=sV5[2][d], v3=sV5[3][d], v4=sV5[4][d];
      #pragma unroll
      for (int j=0;j<4;++j){
        float wo = pWo[(size_t)d*DD + lane + 64*j];
        wa[0][j]+=wo*v0; wa[1][j]+=wo*v1; wa[2][j]+=wo*v2; wa[3][j]+=wo*v3; wa[4][j]+=wo*v4;
      }
    }
    #pragma unroll
    for (int c=0;c<NC;++c){
      #pragma unroll
      for (int j=0;j<4;++j)
        W5[ub + (size_t)c*HH*DD + 64*j] = wa[c][j];
    }
  }
}

// 8 named partials (one per h) -> lane holds full sum for h=lane>>3.
__device__ __forceinline__ float reduce40(
  float q0,float q1,float q2,float q3,float q4,float q5,float q6,float q7,int lane)
{
  const bool b5 = (lane&32)!=0, b4 = (lane&16)!=0, b3 = (lane&8)!=0;
  float r0 = (b5? q4:q0) + __shfl_xor(b5? q0:q4, 32);
  float r1 = (b5? q5:q1) + __shfl_xor(b5? q1:q5, 32);
  float r2 = (b5? q6:q2) + __shfl_xor(b5? q2:q6, 32);
  float r3 = (b5? q7:q3) + __shfl_xor(b5? q3:q7, 32);
  float t0 = (b4? r2:r0) + __shfl_xor(b4? r0:r2, 16);
  float t1 = (b4? r3:r1) + __shfl_xor(b4? r1:r3, 16);
  float s  = (b3? t1:t0) + __shfl_xor(b3? t0:t1, 8);
  s += __shfl_xor(s,4); s += __shfl_xor(s,2); s += __shfl_xor(s,1);
  return s;
}

// one candidate-block score for one row from a global/LDS base
__device__ __forceinline__ float dotred(const float* base, float xa, float xb,
                                        float xc, float xd, int lane)
{
  const float* ub = base + 4*lane;
  float4 u;
  u=*(const float4*)(ub+0*DD); float q0=xa*u.x+xb*u.y+xc*u.z+xd*u.w;
  u=*(const float4*)(ub+1*DD); float q1=xa*u.x+xb*u.y+xc*u.z+xd*u.w;
  u=*(const float4*)(ub+2*DD); float q2=xa*u.x+xb*u.y+xc*u.z+xd*u.w;
  u=*(const float4*)(ub+3*DD); float q3=xa*u.x+xb*u.y+xc*u.z+xd*u.w;
  u=*(const float4*)(ub+4*DD); float q4=xa*u.x+xb*u.y+xc*u.z+xd*u.w;
  u=*(const float4*)(ub+5*DD); float q5=xa*u.x+xb*u.y+xc*u.z+xd*u.w;
  u=*(const float4*)(ub+6*DD); float q6=xa*u.x+xb*u.y+xc*u.z+xd*u.w;
  u=*(const float4*)(ub+7*DD); float q7=xa*u.x+xb*u.y+xc*u.z+xd*u.w;
  return reduce40(q0,q1,q2,q3,q4,q5,q6,q7,lane);
}

// One block per batch, 512 threads = 8 waves. Each wave: 8 iterations of a
// 2-row pair (n, n+64) so every U5/W5 ds_read feeds 2 rows.
// __launch_bounds__(512, 2): VGPR cap >=128 (the (512,4) cap of 64 caused
// rounds 4/7 to spill ~1.9 GB of scratch traffic). LDS 80KB -> 2 blocks/CU.
__global__ __launch_bounds__(512, 2) void main_kernel(
  const float* __restrict__ tokens, const int* __restrict__ ego_idx,
  const float* __restrict__ v2g, const int* __restrict__ candI,
  const float* __restrict__ U5g, const float* __restrict__ eU5g,
  const float* __restrict__ W5g, const float* __restrict__ biasO,
  const float* __restrict__ ln2_g, const float* __restrict__ ln2_b,
  float* __restrict__ out)
{
  __shared__ float sU[NC*HH*DD];
  __shared__ float sW[NC*HH*DD];
  int b = blockIdx.x, t = threadIdx.x;
  int lane = t & 63, wave = t >> 6;
  {
    const float4* srcU = (const float4*)(U5g + (size_t)b*NC*HH*DD);
    const float4* srcW = (const float4*)(W5g + (size_t)b*NC*HH*DD);
    float4* dU = (float4*)sU; float4* dW = (float4*)sW;
    #pragma unroll
    for (int i=0;i<5;++i){ dU[t+512*i]=srcU[t+512*i]; dW[t+512*i]=srcW[t+512*i]; }
  }
  int ego = ego_idx[b];
  const int* cip = candI + b*8;
  int ci0=cip[0],ci1=cip[1],ci2=cip[2],ci3=cip[3],ci4=cip[4];
  float4 v2r = *(const float4*)(v2g + (size_t)b*DD + 4*lane);
  float4 g4  = *(const float4*)(ln2_g + 4*lane);
  float4 b4  = *(const float4*)(ln2_b + 4*lane);
  int h_lane = lane>>3;
  __syncthreads();

  for (int g=0; g<8; ++g){
    int nA = wave + 8*g, nB = nA + 64;
    float4 tA = *(const float4*)(tokens + ((size_t)b*NN+nA)*DD + 4*lane);
    float4 tB = *(const float4*)(tokens + ((size_t)b*NN+nB)*DD + 4*lane);
    const float* bpA = biasO + ((size_t)b*NN+nA)*NC*HH + h_lane;
    const float* bpB = biasO + ((size_t)b*NN+nB)*NC*HH + h_lane;
    float biA0=bpA[0], biA1=bpA[8], biA2=bpA[16], biA3=bpA[24], biA4=bpA[32];
    float biB0=bpB[0], biB1=bpB[8], biB2=bpB[16], biB3=bpB[24], biB4=bpB[32];
    float hA0=tA.x+v2r.x, hA1=tA.y+v2r.y, hA2=tA.z+v2r.z, hA3=tA.w+v2r.w;
    float hB0=tB.x+v2r.x, hB1=tB.y+v2r.y, hB2=tB.z+v2r.z, hB3=tB.w+v2r.w;
    float s1A=hA0+hA1+hA2+hA3, s2A=hA0*hA0+hA1*hA1+hA2*hA2+hA3*hA3;
    float s1B=hB0+hB1+hB2+hB3, s2B=hB0*hB0+hB1*hB1+hB2*hB2+hB3*hB3;
    #pragma unroll
    for (int m=32;m>=1;m>>=1){
      s1A+=__shfl_xor(s1A,m); s2A+=__shfl_xor(s2A,m);
      s1B+=__shfl_xor(s1B,m); s2B+=__shfl_xor(s2B,m);
    }
    float muA=s1A*(1.0f/DD), varA=s2A*(1.0f/DD)-muA*muA, rsA=rsqrtf(varA+1e-5f);
    float muB=s1B*(1.0f/DD), varB=s2B*(1.0f/DD)-muB*muB, rsB=rsqrtf(varB+1e-5f);
    float xA0=(hA0-muA)*rsA*g4.x+b4.x, xA1=(hA1-muA)*rsA*g4.y+b4.y;
    float xA2=(hA2-muA)*rsA*g4.z+b4.z, xA3=(hA3-muA)*rsA*g4.w+b4.w;
    float xB0=(hB0-muB)*rsB*g4.x+b4.x, xB1=(hB1-muB)*rsB*g4.y+b4.y;
    float xB2=(hB2-muB)*rsB*g4.z+b4.z, xB3=(hB3-muB)*rsB*g4.w+b4.w;
    float scA0,scA1,scA2,scA3,scA4, scB0,scB1,scB2,scB3,scB4;
#define DOT8P(BASE, RA, RB) { \
    const float* ub_ = (BASE) + 4*lane; float4 u_; \
    float qA0,qA1,qA2,qA3,qA4,qA5,qA6,qA7, qB0,qB1,qB2,qB3,qB4,qB5,qB6,qB7; \
    u_=*(const float4*)(ub_+0*DD); qA0=xA0*u_.x+xA1*u_.y+xA2*u_.z+xA3*u_.w; qB0=xB0*u_.x+xB1*u_.y+xB2*u_.z+xB3*u_.w; \
    u_=*(const float4*)(ub_+1*DD); qA1=xA0*u_.x+xA1*u_.y+xA2*u_.z+xA3*u_.w; qB1=xB0*u_.x+xB1*u_.y+xB2*u_.z+xB3*u_.w; \
    u_=*(const float4*)(ub_+2*DD); qA2=xA0*u_.x+xA1*u_.y+xA2*u_.z+xA3*u_.w; qB2=xB0*u_.x+xB1*u_.y+xB2*u_.z+xB3*u_.w; \
    u_=*(const float4*)(ub_+3*DD); qA3=xA0*u_.x+xA1*u_.y+xA2*u_.z+xA3*u_.w; qB3=xB0*u_.x+xB1*u_.y+xB2*u_.z+xB3*u_.w; \
    u_=*(const float4*)(ub_+4*DD); qA4=xA0*u_.x+xA1*u_.y+xA2*u_.z+xA3*u_.w; qB4=xB0*u_.x+xB1*u_.y+xB2*u_.z+xB3*u_.w; \
    u_=*(const float4*)(ub_+5*DD); qA5=xA0*u_.x+xA1*u_.y+xA2*u_.z+xA3*u_.w; qB5=xB0*u_.x+xB1*u_.y+xB2*u_.z+xB3*u_.w; \
    u_=*(const float4*)(ub_+6*DD); qA6=xA0*u_.x+xA1*u_.y+xA2*u_.z+xA3*u_.w; qB6=xB0*u_.x+xB1*u_.y+xB2*u_.z+xB3*u_.w; \
    u_=*(const float4*)(ub_+7*DD); qA7=xA0*u_.x+xA1*u_.y+xA2*u_.z+xA3*u_.w; qB7=xB0*u_.x+xB1*u_.y+xB2*u_.z+xB3*u_.w; \
    RA = reduce40(qA0,qA1,qA2,qA3,qA4,qA5,qA6,qA7,lane); \
    RB = reduce40(qB0,qB1,qB2,qB3,qB4,qB5,qB6,qB7,lane); }
    DOT8P(sU + 0*HH*DD, scA0, scB0)
    DOT8P(sU + 1*HH*DD, scA1, scB1)
    DOT8P(sU + 2*HH*DD, scA2, scB2)
    DOT8P(sU + 3*HH*DD, scA3, scB3)
    DOT8P(sU + 4*HH*DD, scA4, scB4)
#undef DOT8P
    if (nA==ego){
      const float* eb = eU5g + (size_t)b*NC*HH*DD;
      scA0 = dotred(eb+0*HH*DD, xA0,xA1,xA2,xA3, lane);
      scA1 = dotred(eb+1*HH*DD, xA0,xA1,xA2,xA3, lane);
      scA2 = dotred(eb+2*HH*DD, xA0,xA1,xA2,xA3, lane);
      scA3 = dotred(eb+3*HH*DD, xA0,xA1,xA2,xA3, lane);
      scA4 = dotred(eb+4*HH*DD, xA0,xA1,xA2,xA3, lane);
    }
    if (nB==ego){
      const float* eb = eU5g + (size_t)b*NC*HH*DD;
      scB0 = dotred(eb+0*HH*DD, xB0,xB1,xB2,xB3, lane);
      scB1 = dotred(eb+1*HH*DD, xB0,xB1,xB2,xB3, lane);
      scB2 = dotred(eb+2*HH*DD, xB0,xB1,xB2,xB3, lane);
      scB3 = dotred(eb+3*HH*DD, xB0,xB1,xB2,xB3, lane);
      scB4 = dotred(eb+4*HH*DD, xB0,xB1,xB2,xB3, lane);
    }
    // ---- mask + softmax row A ----
    {
      int pos = (ci0==nA)?0:(ci1==nA)?1:(ci2==nA)?2:(ci3==nA)?3:(ci4==nA)?4:5;
      int bad = (pos==5)?4:pos;
      scA0 = (bad==0)? -1e30f : scA0+biA0;
      scA1 = (bad==1)? -1e30f : scA1+biA1;
      scA2 = (bad==2)? -1e30f : scA2+biA2;
      scA3 = (bad==3)? -1e30f : scA3+biA3;
      scA4 = (bad==4)? -1e30f : scA4+biA4;
      float mx = fmaxf(fmaxf(fmaxf(scA0,scA1),fmaxf(scA2,scA3)),scA4);
      float e0=__expf(scA0-mx), e1=__expf(scA1-mx), e2=__expf(scA2-mx);
      float e3=__expf(scA3-mx), e4=__expf(scA4-mx);
      float inv = 1.0f/(e0+e1+e2+e3+e4);
      scA0=e0*inv; scA1=e1*inv; scA2=e2*inv; scA3=e3*inv; scA4=e4*inv;
    }
    // ---- mask + softmax row B ----
    {
      int pos = (ci0==nB)?0:(ci1==nB)?1:(ci2==nB)?2:(ci3==nB)?3:(ci4==nB)?4:5;
      int bad = (pos==5)?4:pos;
      scB0 = (bad==0)? -1e30f : scB0+biB0;
      scB1 = (bad==1)? -1e30f : scB1+biB1;
      scB2 = (bad==2)? -1e30f : scB2+biB2;
      scB3 = (bad==3)? -1e30f : scB3+biB3;
      scB4 = (bad==4)? -1e30f : scB4+biB4;
      float mx = fmaxf(fmaxf(fmaxf(scB0,scB1),fmaxf(scB2,scB3)),scB4);
      float e0=__expf(scB0-mx), e1=__expf(scB1-mx), e2=__expf(scB2-mx);
      float e3=__expf(scB3-mx), e4=__expf(scB4-mx);
      float inv = 1.0f/(e0+e1+e2+e3+e4);
      scB0=e0*inv; scB1=e1*inv; scB2=e2*inv; scB3=e3*inv; scB4=e4*inv;
    }
    // ---- output: each W5 read feeds both rows; weight broadcast via
    //      readlane (SALU pipe, frees the DS pipe) ----
    float oA0=0,oA1=0,oA2=0,oA3=0, oB0=0,oB1=0,oB2=0,oB3=0;
    #pragma unroll
    for (int c=0;c<NC;++c){
      float wcA = (c==0)?scA0:(c==1)?scA1:(c==2)?scA2:(c==3)?scA3:scA4;
      float wcB = (c==0)?scB0:(c==1)?scB1:(c==2)?scB2:(c==3)?scB3:scB4;
      #pragma unroll
      for (int h=0;h<HH;++h){
        const float4 wr = *(const float4*)(sW + (c*HH+h)*DD + 4*lane);
        float wvA = __int_as_float(
            __builtin_amdgcn_readlane(__float_as_int(wcA), h*8));
        float wvB = __int_as_float(
            __builtin_amdgcn_readlane(__float_as_int(wcB), h*8));
        oA0+=wvA*wr.x; oA1+=wvA*wr.y; oA2+=wvA*wr.z; oA3+=wvA*wr.w;
        oB0+=wvB*wr.x; oB1+=wvB*wr.y; oB2+=wvB*wr.z; oB3+=wvB*wr.w;
      }
    }
    *(float4*)(out + ((size_t)b*NN+nA)*DD + 4*lane) =
        make_float4(hA0+oA0, hA1+oA1, hA2+oA2, hA3+oA3);
    *(float4*)(out + ((size_t)b*NN+nB)*DD + 4*lane) =
        make_float4(hB0+oB0, hB1+oB1, hB2+oB2, hB3+oB3);
  }
}

extern "C" void kernel_launch(void* const* d_in, const int* in_sizes, int n_in,
                              void* d_out, int out_size, void* d_ws, size_t ws_size,
                              hipStream_t stream) {
  (void)in_sizes; (void)n_in; (void)out_size; (void)ws_size;
  const float* tokens = (const float*)d_in[0];
  const int*   ego_idx= (const int*)  d_in[1];
  const float* dist   = (const float*)d_in[2];
  // d_in[3] = ego_speed (unused by reference)
  const float* ln1_g  = (const float*)d_in[4];
  const float* ln1_b  = (const float*)d_in[5];
  const float* ln2_g  = (const float*)d_in[6];
  const float* ln2_b  = (const float*)d_in[7];
  // d_in[8]=cWq, d_in[9]=cWk dead: softmax over singleton axis == 1
  const float* cWv    = (const float*)d_in[10];
  const float* cWo    = (const float*)d_in[11];
  const float* pWq    = (const float*)d_in[12];
  const float* eWq    = (const float*)d_in[13];
  const float* pWk    = (const float*)d_in[14];
  const float* pWv    = (const float*)d_in[15];
  const float* pWo    = (const float*)d_in[16];
  const float* bW1    = (const float*)d_in[17];
  const float* bb1    = (const float*)d_in[18];
  const float* bW2    = (const float*)d_in[19];
  const float* bb2    = (const float*)d_in[20];
  float* outp = (float*)d_out;

  char* w = (char*)d_ws;
  float* v2g   = (float*)w; w += (size_t)BB*DD*4;
  int*   candI = (int*)w;   w += (size_t)BB*8*4;
  float* U5    = (float*)w; w += (size_t)BB*NC*HH*DD*4;
  float* eU5   = (float*)w; w += (size_t)BB*NC*HH*DD*4;
  float* W5    = (float*)w; w += (size_t)BB*NC*HH*DD*4;
  float* biasO = (float*)w; w += (size_t)BB*NN*NC*HH*4;
  float* pWqT  = (float*)w; w += (size_t)DD*DD*4;
  float* eWqT  = (float*)w; w += (size_t)DD*DD*4;

  transpose_kernel<<<dim3(8,8,2), dim3(256), 0, stream>>>(pWq, eWq, pWqT, eWqT);

  prep1_kernel<<<dim3(BB), dim3(512), 0, stream>>>(
      tokens, ego_idx, dist, ln1_g, ln1_b, cWv, cWo,
      bW1, bb1, bW2, bb2, v2g, candI, biasO);

  prep2_kernel<<<dim3(BB), dim3(512), 0, stream>>>(
      tokens, ln2_g, ln2_b, pWqT, eWqT, pWk, pWv, pWo,
      v2g, candI, U5, eU5, W5);

  main_kernel<<<dim3(BB), dim3(512), 0, stream>>>(
      tokens, ego_idx, v2g, candI, U5, eU5, W5, biasO, ln2_g, ln2_b, outp);
}